// Round 6
// baseline (319.284 us; speedup 1.0000x reference)
//
#include <hip/hip_runtime.h>
#include <hip/hip_bf16.h>

// GraphConvolution: out = relu( (W@x + b) @ adj^T + x ), B=4096, C=256, N=25.
// R6: latency-chain attack on R5 (102us, all pipes <21%, 2 blocks/CU).
//  - in-place epilogue into xs + fused store+stage phase -> outS deleted,
//    LDS 74.7->48KB -> 3 blocks/CU (12 waves) at VGPR<=168 (af streamed, not pinned)
//  - register prefetch of next batch's x-tile overlaps the whole batch pipeline
//  - NB=4 (grid 1024): more independent streams per CU
// All global accesses remain fully coalesced (R5's verified win).

#define BATCH 4096
#define C 256
#define N 25
#define NB 4
#define XSTR 28      // xs fp32 row stride (112 B, 16B-aligned rows)
#define YSTR 264     // ys bf16 row stride (528 B, 16B-aligned rows)
#define NCH 7        // float4 chunks per thread for the 25600 B x/out tile

typedef __bf16 bf16x8 __attribute__((ext_vector_type(8)));
typedef float f32x4 __attribute__((ext_vector_type(4)));

// ---- prep: Wshuf[frag][lane] = exact MFMA A-fragment bytes; adjS = rowsums ----
__global__ void prep_kernel(const float* __restrict__ W, const float* __restrict__ adj,
                            bf16x8* __restrict__ Wshuf, float* __restrict__ adjS) {
    int i = blockIdx.x * 256 + threadIdx.x;       // 8192 = 128 frags x 64 lanes
    int f = i >> 6, l = i & 63;
    int wv = f >> 5, kk = (f >> 2) & 7, ot = f & 3;
    int quad = l >> 4, l15 = l & 15;
    int o = wv * 64 + ot * 16 + l15;
    int cb = kk * 32 + quad * 8;
    bf16x8 v;
    #pragma unroll
    for (int j = 0; j < 8; ++j) v[j] = (__bf16)W[o * C + cb + j];
    Wshuf[i] = v;
    if (blockIdx.x == 0 && threadIdx.x < 32) {
        float s = 0.f;
        if (threadIdx.x < N)
            for (int n = 0; n < N; ++n) s += adj[threadIdx.x * N + n];
        adjS[threadIdx.x] = s;
    }
}

__global__ __launch_bounds__(256, 3) void gcn_kernel(
    const float* __restrict__ x, const float* __restrict__ adj,
    const float* __restrict__ bias, const float* __restrict__ adjSg,
    const bf16x8* __restrict__ Wshuf, float* __restrict__ out)
{
    __shared__ __align__(16) float  xs[C * XSTR];   // 28672 B: x tile, then out tile (in-place)
    __shared__ __align__(16) __bf16 ys[32 * YSTR];  // 16896 B
    __shared__ __align__(16) __bf16 adjbf[32 * 40]; //  2560 B
    __shared__ float biasS[C];                      //  1024 B  => 49152 B -> 3 blocks/CU

    const int tid = threadIdx.x;
    const int wv = tid >> 6, lane = tid & 63;
    const int quad = lane >> 4, l15 = lane & 15;
    const int o0 = wv * 64;
    const int b0 = blockIdx.x * NB;

    // ---- prefetch batch 0's x tile into registers (coalesced float4) ----
    float4 pf[NCH];
    {
        const float4* xb4 = (const float4*)(x + (size_t)b0 * (C * N));
        #pragma unroll
        for (int q = 0; q < NCH; ++q) {
            int i4 = q * 256 + tid;
            if (i4 < (C * N) / 4) pf[q] = xb4[i4];
        }
    }

    // ---- setup: adj (zero-padded), bias ----
    for (int e = tid; e < N * N; e += 256) {
        int m = e / N, n = e - m * N;
        adjbf[m * 40 + n] = (__bf16)adj[e];
    }
    if (tid < N) {
        #pragma unroll
        for (int n = N; n < 32; ++n) adjbf[tid * 40 + n] = (__bf16)0.f;
    } else if (tid < 32) {
        #pragma unroll
        for (int n = 0; n < 32; ++n) adjbf[tid * 40 + n] = (__bf16)0.f;
    }
    biasS[tid] = bias[tid];
    const float aS0 = adjSg[l15];
    const float aS1 = adjSg[16 + l15];
    __syncthreads();

    const bf16x8 a0 = *(const bf16x8*)&adjbf[l15 * 40 + quad * 8];
    const bf16x8 a1 = *(const bf16x8*)&adjbf[(16 + l15) * 40 + quad * 8];

    #pragma unroll 1
    for (int bi = 0; bi < NB; ++bi) {
        // ---- fused STORE(bi-1) + STAGE(bi): same thread reads out-vals and
        // rewrites the same xs addresses with next x; bijective map, no race ----
        {
            float4* outp = (float4*)(out + (size_t)(b0 + bi - 1) * (C * N)); // valid for bi>0
            #pragma unroll
            for (int q = 0; q < NCH; ++q) {
                int i4 = q * 256 + tid;
                if (i4 < (C * N) / 4) {
                    int e = i4 * 4;
                    int cc = e / N, nn = e - cc * N;
                    int addr = cc * XSTR + nn;
                    float fv[4] = {pf[q].x, pf[q].y, pf[q].z, pf[q].w};
                    float rv[4];
                    #pragma unroll
                    for (int j = 0; j < 4; ++j) {
                        rv[j] = xs[addr];          // out value of batch bi-1 (garbage at bi==0, unused)
                        xs[addr] = fv[j];          // stage x(bi)
                        ++nn; ++addr;
                        if (nn == N) { nn = 0; addr += XSTR - N; }
                    }
                    if (bi > 0) outp[i4] = make_float4(rv[0], rv[1], rv[2], rv[3]);
                }
            }
        }
        // ---- prefetch next batch's x while everything below executes ----
        if (bi + 1 < NB) {
            const float4* xn4 = (const float4*)(x + (size_t)(b0 + bi + 1) * (C * N));
            #pragma unroll
            for (int q = 0; q < NCH; ++q) {
                int i4 = q * 256 + tid;
                if (i4 < (C * N) / 4) pf[q] = xn4[i4];
            }
        }
        __syncthreads();   // B1: xs = x(bi)

        // ---- agg MFMA: y[m][c] = sum_n adj[m][n]*x[c][n]; frags from LDS ----
        {
            f32x4 yacc[4][2];
            #pragma unroll
            for (int ctl = 0; ctl < 4; ++ctl) {
                const int c = o0 + ctl * 16 + l15;
                bf16x8 xf;
                if (quad < 3) {
                    f32x4 u = *(const f32x4*)&xs[c * XSTR + quad * 8];
                    f32x4 w = *(const f32x4*)&xs[c * XSTR + quad * 8 + 4];
                    xf[0] = (__bf16)u[0]; xf[1] = (__bf16)u[1]; xf[2] = (__bf16)u[2]; xf[3] = (__bf16)u[3];
                    xf[4] = (__bf16)w[0]; xf[5] = (__bf16)w[1]; xf[6] = (__bf16)w[2]; xf[7] = (__bf16)w[3];
                } else {
                    float u = xs[c * XSTR + 24];
                    xf[0] = (__bf16)u;
                    #pragma unroll
                    for (int j = 1; j < 8; ++j) xf[j] = (__bf16)0.f;
                }
                yacc[ctl][0] = __builtin_amdgcn_mfma_f32_16x16x32_bf16(a0, xf, (f32x4)0.f, 0, 0, 0);
                yacc[ctl][1] = __builtin_amdgcn_mfma_f32_16x16x32_bf16(a1, xf, (f32x4)0.f, 0, 0, 0);
            }
            #pragma unroll
            for (int ctl = 0; ctl < 4; ++ctl) {
                const int c = o0 + ctl * 16 + l15;
                #pragma unroll
                for (int mt = 0; mt < 2; ++mt)
                    #pragma unroll
                    for (int r = 0; r < 4; ++r)
                        ys[(mt * 16 + quad * 4 + r) * YSTR + c] = (__bf16)yacc[ctl][mt][r];
            }
        }
        __syncthreads();   // B2: ys ready

        // ---- main GEMM (af streamed, coalesced L2-hot Wshuf) + in-place epilogue ----
        {
            f32x4 acc[4][2];
            #pragma unroll
            for (int ot = 0; ot < 4; ++ot) { acc[ot][0] = (f32x4)0.f; acc[ot][1] = (f32x4)0.f; }
            #pragma unroll
            for (int kk = 0; kk < 8; ++kk) {
                bf16x8 bfr0 = *(const bf16x8*)&ys[l15 * YSTR + kk * 32 + quad * 8];
                bf16x8 bfr1 = *(const bf16x8*)&ys[(16 + l15) * YSTR + kk * 32 + quad * 8];
                #pragma unroll
                for (int ot = 0; ot < 4; ++ot) {
                    bf16x8 af = Wshuf[((wv * 8 + kk) * 4 + ot) * 64 + lane];
                    acc[ot][0] = __builtin_amdgcn_mfma_f32_16x16x32_bf16(af, bfr0, acc[ot][0], 0, 0, 0);
                    acc[ot][1] = __builtin_amdgcn_mfma_f32_16x16x32_bf16(af, bfr1, acc[ot][1], 0, 0, 0);
                }
            }
            #pragma unroll
            for (int ot = 0; ot < 4; ++ot)
                #pragma unroll
                for (int r = 0; r < 4; ++r) {
                    const int o = o0 + ot * 16 + quad * 4 + r;
                    const float bia = biasS[o];
                    {   // m = l15 < 16
                        const int m = l15;
                        float v = acc[ot][0][r] + bia * aS0 + xs[o * XSTR + m];
                        xs[o * XSTR + m] = v > 0.f ? v : 0.f;   // in-place: xs becomes out tile
                    }
                    if (l15 < N - 16) {   // m = 16+l15 < 25
                        const int m = 16 + l15;
                        float v = acc[ot][1][r] + bia * aS1 + xs[o * XSTR + m];
                        xs[o * XSTR + m] = v > 0.f ? v : 0.f;
                    }
                }
        }
        __syncthreads();   // B3: xs = out(bi)
    }

    // ---- final store: out(NB-1) from xs, coalesced ----
    {
        float4* outp = (float4*)(out + (size_t)(b0 + NB - 1) * (C * N));
        #pragma unroll
        for (int q = 0; q < NCH; ++q) {
            int i4 = q * 256 + tid;
            if (i4 < (C * N) / 4) {
                int e = i4 * 4;
                int cc = e / N, nn = e - cc * N;
                int addr = cc * XSTR + nn;
                float rv[4];
                #pragma unroll
                for (int j = 0; j < 4; ++j) {
                    rv[j] = xs[addr];
                    ++nn; ++addr;
                    if (nn == N) { nn = 0; addr += XSTR - N; }
                }
                outp[i4] = make_float4(rv[0], rv[1], rv[2], rv[3]);
            }
        }
    }
}

extern "C" void kernel_launch(void* const* d_in, const int* in_sizes, int n_in,
                              void* d_out, int out_size, void* d_ws, size_t ws_size,
                              hipStream_t stream) {
    (void)in_sizes; (void)n_in; (void)out_size; (void)ws_size;
    const float* x    = (const float*)d_in[0];   // [4096, 256, 25]
    const float* adj  = (const float*)d_in[1];   // [25, 25]
    const float* W    = (const float*)d_in[2];   // [256, 256]
    const float* bias = (const float*)d_in[3];   // [256]
    float* out = (float*)d_out;

    unsigned char* ws = (unsigned char*)d_ws;
    bf16x8* Wshuf = (bf16x8*)ws;                 // 131072 B
    float*  adjS  = (float*)(ws + 131072);       // 128 B

    prep_kernel<<<32, 256, 0, stream>>>(W, adj, Wshuf, adjS);
    gcn_kernel<<<BATCH / NB, 256, 0, stream>>>(x, adj, bias, adjS, Wshuf, out);
}